// Round 3
// baseline (3336.110 us; speedup 1.0000x reference)
//
#include <hip/hip_runtime.h>
#include <math.h>

// FermiNet Ansatz_fb forward, fully fused: 1 block (256 thr) per walker.
// R3: f32 numerics everywhere (bf16 p_v reverted — it broke slogdet),
// double-buffered register prefetch on all weight k-loops, float4 LDS reads,
// single-pass p-stream, fast tanh. 2 blocks/CU (LDS 80KB) -> VGPRs<=256 free.

namespace {

constexpr float SQRT3 = 1.7320508075688772f;

__device__ __forceinline__ float tanh_fast(float x) {
  float e = __expf(2.f * x);
  return 1.f - 2.f * __builtin_amdgcn_rcpf(e + 1.f);
}

__global__ __launch_bounds__(256, 2) void ansatz_fused(
    const float* __restrict__ r,     // [B,20,3]
    const float* __restrict__ a_g,   // [4,3]
    const float* __restrict__ s_w0,  // [56,256]
    const float* __restrict__ s_b0,  // [256]
    const float* __restrict__ s_w,   // [3,832,256]
    const float* __restrict__ s_b,   // [3,256]
    const float* __restrict__ p_w0,  // [4,32]
    const float* __restrict__ p_b0,  // [32]
    const float* __restrict__ p_w,   // [3,32,32]
    const float* __restrict__ p_b,   // [3,32]
    const float* __restrict__ vu_w, const float* __restrict__ vu_b,
    const float* __restrict__ vd_w, const float* __restrict__ vd_b,
    const float* __restrict__ wu_w, const float* __restrict__ wu_b,
    const float* __restrict__ wd_w, const float* __restrict__ wd_b,
    const float* __restrict__ wf_w,  // [16]
    float* __restrict__ out)         // [B]
{
  const int b = blockIdx.x;
  const int tid = threadIdx.x;

  __shared__ __align__(16) float svT[256 * 20];   // 20480 B (later: orb)
  __shared__ __align__(16) float pv[12800];       // 51200 B (later: suT/sdT)
  __shared__ __align__(16) float mu[256], md[256];
  __shared__ __align__(16) float puT[640], pdT[640];
  __shared__ float lenT[80];
  __shared__ float rl[20][3];
  __shared__ float apos[4][3];
  __shared__ float expv[20];
  __shared__ float lu_s[32], sg_s[32];

  // ---- geometry ----
  if (tid < 60) (&rl[0][0])[tid] = r[b * 60 + tid];
  if (tid >= 64 && tid < 76) (&apos[0][0])[tid - 64] = a_g[tid - 64];
  __syncthreads();

  if (tid < 80) {
    int at = tid / 20, e = tid % 20;
    float dx = rl[e][0] - apos[at][0];
    float dy = rl[e][1] - apos[at][1];
    float dz = rl[e][2] - apos[at][2];
    lenT[tid] = sqrtf(dx * dx + dy * dy + dz * dz);
  }
  // layer-0 pair means directly from geometry
  if (tid < 160) {
    int half = tid / 80, rem = tid % 80, c = rem / 20, j2 = rem % 20;
    float s = 0.f;
    for (int i = half * 10; i < half * 10 + 10; ++i) {
      if (c < 3) {
        s += rl[j2][c] - rl[i][c];
      } else if (i == j2) {
        s += SQRT3;
      } else {
        float dx = rl[j2][0] - rl[i][0], dy = rl[j2][1] - rl[i][1], dz = rl[j2][2] - rl[i][2];
        s += sqrtf(dx * dx + dy * dy + dz * dz);
      }
    }
    (half ? pdT : puT)[c * 20 + j2] = s * 0.1f;
  }
  __syncthreads();

  if (tid < 20) {
    float s = 0.f;
#pragma unroll
    for (int at = 0; at < 4; ++at) s += __expf(-lenT[at * 20 + tid]);
    expv[tid] = s;
  }
  if (tid < 32) {
    int k = tid & 15, half = tid >> 4;
    int at = k >> 2, comp = k & 3;
    float s = 0.f;
    for (int e = half * 10; e < half * 10 + 10; ++e)
      s += (comp < 3) ? (rl[e][comp] - apos[at][comp]) : lenT[at * 20 + e];
    (half ? md : mu)[k] = s * 0.1f;
  }
  __syncthreads();

  // ---- layer 0, single stream ----
  {
    const int j = tid;
    float w0s[16], wpp[8];
#pragma unroll
    for (int k = 0; k < 16; ++k) w0s[k] = s_w0[k * 256 + j];
#pragma unroll
    for (int c = 0; c < 8; ++c) wpp[c] = s_w0[(48 + c) * 256 + j];
    float accm = s_b0[j];
#pragma unroll
    for (int k = 0; k < 16; ++k)
      accm += mu[k] * s_w0[(16 + k) * 256 + j] + md[k] * s_w0[(32 + k) * 256 + j];
    float sv0[20];
#pragma unroll
    for (int e = 0; e < 20; ++e) {
      float acc = accm;
#pragma unroll
      for (int at = 0; at < 4; ++at) {
        acc += (rl[e][0] - apos[at][0]) * w0s[at * 4 + 0];
        acc += (rl[e][1] - apos[at][1]) * w0s[at * 4 + 1];
        acc += (rl[e][2] - apos[at][2]) * w0s[at * 4 + 2];
        acc += lenT[at * 20 + e] * w0s[at * 4 + 3];
      }
#pragma unroll
      for (int c = 0; c < 4; ++c)
        acc += puT[c * 20 + e] * wpp[c] + pdT[c * 20 + e] * wpp[4 + c];
      sv0[e] = tanh_fast(acc);
    }
#pragma unroll
    for (int e = 0; e < 20; ++e) svT[j * 20 + e] = sv0[e];
  }
  // ---- layer 0, pair stream ----
  {
    const int c = tid & 31;
    float pw0c[4];
#pragma unroll
    for (int k = 0; k < 4; ++k) pw0c[k] = p_w0[k * 32 + c];
    const float pb0c = p_b0[c];
    for (int s = 0; s < 50; ++s) {
      int o = tid + 256 * s;
      int ij = o >> 5, i = ij / 20, j2 = ij % 20;
      float dx = rl[j2][0] - rl[i][0], dy = rl[j2][1] - rl[i][1], dz = rl[j2][2] - rl[i][2];
      float len = (i == j2) ? SQRT3 : sqrtf(dx * dx + dy * dy + dz * dz);
      pv[o] = tanh_fast(pb0c + dx * pw0c[0] + dy * pw0c[1] + dz * pw0c[2] + len * pw0c[3]);
    }
  }
  __syncthreads();

  // ---- residual layers + final means pass ----
  for (int l = 0; l < 4; ++l) {
    // s means (float4 reads of own row)
    {
      const float4* svr = (const float4*)&svT[tid * 20];
      float4 a0 = svr[0], a1 = svr[1], a2 = svr[2], a3 = svr[3], a4 = svr[4];
      mu[tid] = (a0.x + a0.y + a0.z + a0.w + a1.x + a1.y + a1.z + a1.w + a2.x + a2.y) * 0.1f;
      md[tid] = (a2.z + a2.w + a3.x + a3.y + a3.z + a3.w + a4.x + a4.y + a4.z + a4.w) * 0.1f;
    }
    // pair means
#pragma unroll
    for (int t5 = 0; t5 < 5; ++t5) {
      int t = tid + 256 * t5;
      int half = t / 640, rem = t % 640, j2 = rem >> 5, c = rem & 31;
      int base = half * 6400 + j2 * 32 + c;
      float s = 0.f;
#pragma unroll
      for (int i = 0; i < 10; ++i) s += pv[base + i * 640];
      (half ? pdT : puT)[c * 20 + j2] = s * 0.1f;
    }
    __syncthreads();
    if (l == 3) break;

    const float* Wj = s_w + l * 832 * 256 + tid;
    const float* PW = p_w + l * 1024;

    // ---- single stream: thread j = tid owns output column j ----
    float sacc[20];
#pragma unroll
    for (int e = 0; e < 20; ++e) sacc[e] = 0.f;
    float m0 = 0.f, m1 = 0.f, m2 = 0.f, m3 = 0.f;
    {
      float As[8], Au[8], Ad[8], Bs[8], Bu[8], Bd[8];
#pragma unroll
      for (int i = 0; i < 8; ++i) {
        As[i] = Wj[i * 256]; Au[i] = Wj[(256 + i) * 256]; Ad[i] = Wj[(512 + i) * 256];
      }
      for (int k0 = 0; k0 < 256; k0 += 16) {
        // prefetch B (k0+8)
#pragma unroll
        for (int i = 0; i < 8; ++i) {
          Bs[i] = Wj[(k0 + 8 + i) * 256];
          Bu[i] = Wj[(264 + k0 + i) * 256];
          Bd[i] = Wj[(520 + k0 + i) * 256];
        }
        // compute A (k0)
        {
          float muv[8], mdv[8];
          *(float4*)&muv[0] = *(const float4*)&mu[k0];
          *(float4*)&muv[4] = *(const float4*)&mu[k0 + 4];
          *(float4*)&mdv[0] = *(const float4*)&md[k0];
          *(float4*)&mdv[4] = *(const float4*)&md[k0 + 4];
#pragma unroll
          for (int i = 0; i < 8; i += 2) {
            m0 = fmaf(muv[i], Au[i], m0);     m1 = fmaf(mdv[i], Ad[i], m1);
            m2 = fmaf(muv[i + 1], Au[i + 1], m2); m3 = fmaf(mdv[i + 1], Ad[i + 1], m3);
          }
#pragma unroll
          for (int i = 0; i < 8; ++i) {
            float rr[20];
            const float4* rw = (const float4*)&svT[(k0 + i) * 20];
            *(float4*)&rr[0] = rw[0]; *(float4*)&rr[4] = rw[1]; *(float4*)&rr[8] = rw[2];
            *(float4*)&rr[12] = rw[3]; *(float4*)&rr[16] = rw[4];
            float w = As[i];
#pragma unroll
            for (int e = 0; e < 20; ++e) sacc[e] = fmaf(rr[e], w, sacc[e]);
          }
        }
        // prefetch A (k0+16)
        if (k0 + 16 < 256) {
#pragma unroll
          for (int i = 0; i < 8; ++i) {
            As[i] = Wj[(k0 + 16 + i) * 256];
            Au[i] = Wj[(272 + k0 + i) * 256];
            Ad[i] = Wj[(528 + k0 + i) * 256];
          }
        }
        // compute B (k0+8)
        {
          float muv[8], mdv[8];
          *(float4*)&muv[0] = *(const float4*)&mu[k0 + 8];
          *(float4*)&muv[4] = *(const float4*)&mu[k0 + 12];
          *(float4*)&mdv[0] = *(const float4*)&md[k0 + 8];
          *(float4*)&mdv[4] = *(const float4*)&md[k0 + 12];
#pragma unroll
          for (int i = 0; i < 8; i += 2) {
            m0 = fmaf(muv[i], Bu[i], m0);     m1 = fmaf(mdv[i], Bd[i], m1);
            m2 = fmaf(muv[i + 1], Bu[i + 1], m2); m3 = fmaf(mdv[i + 1], Bd[i + 1], m3);
          }
#pragma unroll
          for (int i = 0; i < 8; ++i) {
            float rr[20];
            const float4* rw = (const float4*)&svT[(k0 + 8 + i) * 20];
            *(float4*)&rr[0] = rw[0]; *(float4*)&rr[4] = rw[1]; *(float4*)&rr[8] = rw[2];
            *(float4*)&rr[12] = rw[3]; *(float4*)&rr[16] = rw[4];
            float w = Bs[i];
#pragma unroll
            for (int e = 0; e < 20; ++e) sacc[e] = fmaf(rr[e], w, sacc[e]);
          }
        }
      }
      // pair contributions, prefetched 4-wide
      float AU[4], AD[4], BU[4], BD[4];
#pragma unroll
      for (int i = 0; i < 4; ++i) { AU[i] = Wj[(768 + i) * 256]; AD[i] = Wj[(800 + i) * 256]; }
      for (int c0 = 0; c0 < 32; c0 += 8) {
#pragma unroll
        for (int i = 0; i < 4; ++i) { BU[i] = Wj[(772 + c0 + i) * 256]; BD[i] = Wj[(804 + c0 + i) * 256]; }
#pragma unroll
        for (int i = 0; i < 4; ++i) {
          float ru[20], rd[20];
          const float4* pu4 = (const float4*)&puT[(c0 + i) * 20];
          const float4* pd4 = (const float4*)&pdT[(c0 + i) * 20];
          *(float4*)&ru[0] = pu4[0]; *(float4*)&ru[4] = pu4[1]; *(float4*)&ru[8] = pu4[2];
          *(float4*)&ru[12] = pu4[3]; *(float4*)&ru[16] = pu4[4];
          *(float4*)&rd[0] = pd4[0]; *(float4*)&rd[4] = pd4[1]; *(float4*)&rd[8] = pd4[2];
          *(float4*)&rd[12] = pd4[3]; *(float4*)&rd[16] = pd4[4];
#pragma unroll
          for (int e = 0; e < 20; ++e) sacc[e] = fmaf(rd[e], AD[i], fmaf(ru[e], AU[i], sacc[e]));
        }
        if (c0 + 8 < 32) {
#pragma unroll
          for (int i = 0; i < 4; ++i) { AU[i] = Wj[(776 + c0 + i) * 256]; AD[i] = Wj[(808 + c0 + i) * 256]; }
        }
#pragma unroll
        for (int i = 0; i < 4; ++i) {
          float ru[20], rd[20];
          const float4* pu4 = (const float4*)&puT[(c0 + 4 + i) * 20];
          const float4* pd4 = (const float4*)&pdT[(c0 + 4 + i) * 20];
          *(float4*)&ru[0] = pu4[0]; *(float4*)&ru[4] = pu4[1]; *(float4*)&ru[8] = pu4[2];
          *(float4*)&ru[12] = pu4[3]; *(float4*)&ru[16] = pu4[4];
          *(float4*)&rd[0] = pd4[0]; *(float4*)&rd[4] = pd4[1]; *(float4*)&rd[8] = pd4[2];
          *(float4*)&rd[12] = pd4[3]; *(float4*)&rd[16] = pd4[4];
#pragma unroll
          for (int e = 0; e < 20; ++e) sacc[e] = fmaf(rd[e], BD[i], fmaf(ru[e], BU[i], sacc[e]));
        }
      }
      float accm = s_b[l * 256 + tid] + ((m0 + m1) + (m2 + m3));
#pragma unroll
      for (int e = 0; e < 20; ++e) sacc[e] = tanh_fast(sacc[e] + accm);
    }
    __syncthreads();
#pragma unroll
    for (int e = 0; e < 20; ++e) svT[tid * 20 + e] += sacc[e];  // residual

    // ---- pair stream: single pass; each wave owns its pairs end-to-end ----
    {
      const int c = tid & 31;
      float pwc[32];
#pragma unroll
      for (int k = 0; k < 32; ++k) pwc[k] = PW[k * 32 + c];
      const float pbc = p_b[l * 32 + c];
      for (int s = 0; s < 50; ++s) {
        int o = tid + 256 * s;
        const float4* q4 = (const float4*)&pv[(o >> 5) << 5];
        float row[32];
#pragma unroll
        for (int q = 0; q < 8; ++q) *(float4*)&row[4 * q] = q4[q];
        float acc = pbc;
#pragma unroll
        for (int k = 0; k < 32; ++k) acc = fmaf(row[k], pwc[k], acc);
        pv[o] = row[c] + tanh_fast(acc);
      }
    }
    __syncthreads();
  }

  // ---- vu/vd heads: suT/sdT overlay the (dead) pv region ----
  float* suT = pv;             // [256][12]
  float* sdT = pv + 256 * 12;
  {
    const int j = tid;
#pragma unroll
    for (int sS = 0; sS < 2; ++sS) {
      const float* Wj = (sS ? vd_w : vu_w) + j;
      const float* Bv = sS ? vd_b : vu_b;
      float* dst = sS ? sdT : suT;
      const int e0 = sS * 10;
      float acc[10];
#pragma unroll
      for (int e = 0; e < 10; ++e) acc[e] = 0.f;
      float m0 = 0.f, m1 = 0.f, m2 = 0.f, m3 = 0.f;
      float As[8], Au[8], Ad[8], Bs[8], Bu[8], Bd[8];
#pragma unroll
      for (int i = 0; i < 8; ++i) {
        As[i] = Wj[i * 256]; Au[i] = Wj[(256 + i) * 256]; Ad[i] = Wj[(512 + i) * 256];
      }
      for (int k0 = 0; k0 < 256; k0 += 16) {
#pragma unroll
        for (int i = 0; i < 8; ++i) {
          Bs[i] = Wj[(k0 + 8 + i) * 256];
          Bu[i] = Wj[(264 + k0 + i) * 256];
          Bd[i] = Wj[(520 + k0 + i) * 256];
        }
        {
          float muv[8], mdv[8];
          *(float4*)&muv[0] = *(const float4*)&mu[k0];
          *(float4*)&muv[4] = *(const float4*)&mu[k0 + 4];
          *(float4*)&mdv[0] = *(const float4*)&md[k0];
          *(float4*)&mdv[4] = *(const float4*)&md[k0 + 4];
#pragma unroll
          for (int i = 0; i < 8; i += 2) {
            m0 = fmaf(muv[i], Au[i], m0);     m1 = fmaf(mdv[i], Ad[i], m1);
            m2 = fmaf(muv[i + 1], Au[i + 1], m2); m3 = fmaf(mdv[i + 1], Ad[i + 1], m3);
          }
#pragma unroll
          for (int i = 0; i < 8; ++i) {
            float rr[20];
            const float4* rw = (const float4*)&svT[(k0 + i) * 20];
            *(float4*)&rr[0] = rw[0]; *(float4*)&rr[4] = rw[1]; *(float4*)&rr[8] = rw[2];
            *(float4*)&rr[12] = rw[3]; *(float4*)&rr[16] = rw[4];
            float w = As[i];
#pragma unroll
            for (int e = 0; e < 10; ++e) acc[e] = fmaf(rr[e0 + e], w, acc[e]);
          }
        }
        if (k0 + 16 < 256) {
#pragma unroll
          for (int i = 0; i < 8; ++i) {
            As[i] = Wj[(k0 + 16 + i) * 256];
            Au[i] = Wj[(272 + k0 + i) * 256];
            Ad[i] = Wj[(528 + k0 + i) * 256];
          }
        }
        {
          float muv[8], mdv[8];
          *(float4*)&muv[0] = *(const float4*)&mu[k0 + 8];
          *(float4*)&muv[4] = *(const float4*)&mu[k0 + 12];
          *(float4*)&mdv[0] = *(const float4*)&md[k0 + 8];
          *(float4*)&mdv[4] = *(const float4*)&md[k0 + 12];
#pragma unroll
          for (int i = 0; i < 8; i += 2) {
            m0 = fmaf(muv[i], Bu[i], m0);     m1 = fmaf(mdv[i], Bd[i], m1);
            m2 = fmaf(muv[i + 1], Bu[i + 1], m2); m3 = fmaf(mdv[i + 1], Bd[i + 1], m3);
          }
#pragma unroll
          for (int i = 0; i < 8; ++i) {
            float rr[20];
            const float4* rw = (const float4*)&svT[(k0 + 8 + i) * 20];
            *(float4*)&rr[0] = rw[0]; *(float4*)&rr[4] = rw[1]; *(float4*)&rr[8] = rw[2];
            *(float4*)&rr[12] = rw[3]; *(float4*)&rr[16] = rw[4];
            float w = Bs[i];
#pragma unroll
            for (int e = 0; e < 10; ++e) acc[e] = fmaf(rr[e0 + e], w, acc[e]);
          }
        }
      }
      float AU[4], AD[4];
      for (int c0 = 0; c0 < 32; c0 += 4) {
#pragma unroll
        for (int i = 0; i < 4; ++i) { AU[i] = Wj[(768 + c0 + i) * 256]; AD[i] = Wj[(800 + c0 + i) * 256]; }
#pragma unroll
        for (int i = 0; i < 4; ++i) {
#pragma unroll
          for (int e = 0; e < 10; ++e)
            acc[e] = fmaf(pdT[(c0 + i) * 20 + e0 + e], AD[i],
                     fmaf(puT[(c0 + i) * 20 + e0 + e], AU[i], acc[e]));
        }
      }
      float accm = Bv[j] + ((m0 + m1) + (m2 + m3));
#pragma unroll
      for (int e = 0; e < 10; ++e) dst[j * 12 + e] = tanh_fast(acc[e] + accm);
    }
  }
  __syncthreads();

  // ---- orbital matrices (orb overlays dead svT) ----
  float* orb = svT;  // [32][100]
  for (int t = tid; t < 320; t += 256) {
    const int mat = t / 160, col = t % 160;
    const float* Wc = (mat ? wd_w : wu_w) + col;
    const float* Bv = mat ? wd_b : wu_b;
    const float* src = mat ? sdT : suT;
    float acc[10];
#pragma unroll
    for (int e = 0; e < 10; ++e) acc[e] = 0.f;
    float wA[8], wB[8];
#pragma unroll
    for (int i = 0; i < 8; ++i) wA[i] = Wc[i * 160];
    for (int k0 = 0; k0 < 256; k0 += 16) {
#pragma unroll
      for (int i = 0; i < 8; ++i) wB[i] = Wc[(k0 + 8 + i) * 160];
#pragma unroll
      for (int i = 0; i < 8; ++i) {
        float rr[12];
        *(float4*)&rr[0] = *(const float4*)&src[(k0 + i) * 12];
        *(float4*)&rr[4] = *(const float4*)&src[(k0 + i) * 12 + 4];
        *(float2*)&rr[8] = *(const float2*)&src[(k0 + i) * 12 + 8];
        float w = wA[i];
#pragma unroll
        for (int e = 0; e < 10; ++e) acc[e] = fmaf(rr[e], w, acc[e]);
      }
      if (k0 + 16 < 256) {
#pragma unroll
        for (int i = 0; i < 8; ++i) wA[i] = Wc[(k0 + 16 + i) * 160];
      }
#pragma unroll
      for (int i = 0; i < 8; ++i) {
        float rr[12];
        *(float4*)&rr[0] = *(const float4*)&src[(k0 + 8 + i) * 12];
        *(float4*)&rr[4] = *(const float4*)&src[(k0 + 8 + i) * 12 + 4];
        *(float2*)&rr[8] = *(const float2*)&src[(k0 + 8 + i) * 12 + 8];
        float w = wB[i];
#pragma unroll
        for (int e = 0; e < 10; ++e) acc[e] = fmaf(rr[e], w, acc[e]);
      }
    }
    const float bb = Bv[col];
    const int d = col / 10, jo = col % 10;
#pragma unroll
    for (int e = 0; e < 10; ++e)
      orb[(mat * 16 + d) * 100 + e * 10 + jo] = (acc[e] + bb) * expv[mat * 10 + e];
  }
  __syncthreads();

  // ---- slogdet: one 10x10 partial-pivot LU per thread ----
  if (tid < 32) {
    float* M = orb + tid * 100;
    float ldet = 0.f, sg = 1.f;
    for (int c = 0; c < 10; ++c) {
      int p = c;
      float mx = fabsf(M[c * 10 + c]);
      for (int rr = c + 1; rr < 10; ++rr) {
        float v = fabsf(M[rr * 10 + c]);
        if (v > mx) { mx = v; p = rr; }
      }
      if (p != c) {
        sg = -sg;
        for (int cc = c; cc < 10; ++cc) {
          float tmp = M[c * 10 + cc];
          M[c * 10 + cc] = M[p * 10 + cc];
          M[p * 10 + cc] = tmp;
        }
      }
      float piv = M[c * 10 + c];
      if (piv < 0.f) sg = -sg;
      ldet += logf(fabsf(piv));
      float inv = 1.f / piv;
      for (int rr = c + 1; rr < 10; ++rr) {
        float f = M[rr * 10 + c] * inv;
        for (int cc = c + 1; cc < 10; ++cc) M[rr * 10 + cc] -= f * M[c * 10 + cc];
      }
    }
    lu_s[tid] = ldet;
    sg_s[tid] = sg;
  }
  __syncthreads();

  if (tid == 0) {
    float mx = -1e30f;
    float l[16], sgn[16];
#pragma unroll
    for (int d = 0; d < 16; ++d) {
      l[d] = lu_s[d] + lu_s[16 + d];
      sgn[d] = sg_s[d] * sg_s[16 + d];
      mx = fmaxf(mx, l[d]);
    }
    float psi = 0.f;
#pragma unroll
    for (int d = 0; d < 16; ++d) psi += sgn[d] * __expf(l[d] - mx) * wf_w[d];
    out[b] = logf(fabsf(psi)) + mx;
  }
}

}  // namespace

extern "C" void kernel_launch(void* const* d_in, const int* in_sizes, int n_in,
                              void* d_out, int out_size, void* d_ws, size_t ws_size,
                              hipStream_t stream) {
  const float* r = (const float*)d_in[0];
  const float* a = (const float*)d_in[1];
  const float* s_w0 = (const float*)d_in[2];
  const float* s_b0 = (const float*)d_in[3];
  const float* s_w = (const float*)d_in[4];
  const float* s_b = (const float*)d_in[5];
  const float* p_w0 = (const float*)d_in[6];
  const float* p_b0 = (const float*)d_in[7];
  const float* p_w = (const float*)d_in[8];
  const float* p_b = (const float*)d_in[9];
  const float* vu_w = (const float*)d_in[10];
  const float* vu_b = (const float*)d_in[11];
  const float* vd_w = (const float*)d_in[12];
  const float* vd_b = (const float*)d_in[13];
  const float* wu_w = (const float*)d_in[14];
  const float* wu_b = (const float*)d_in[15];
  const float* wd_w = (const float*)d_in[16];
  const float* wd_b = (const float*)d_in[17];
  const float* wf_w = (const float*)d_in[18];

  const int nb = in_sizes[0] / 60;  // [B,20,3]
  ansatz_fused<<<dim3(nb), dim3(256), 0, stream>>>(
      r, a, s_w0, s_b0, s_w, s_b, p_w0, p_b0, p_w, p_b,
      vu_w, vu_b, vd_w, vd_b, wu_w, wu_b, wd_w, wd_b, wf_w,
      (float*)d_out);
}

// Round 4
// 2691.556 us; speedup vs baseline: 1.2395x; 1.2395x over previous
//
#include <hip/hip_runtime.h>
#include <math.h>

// FermiNet Ansatz_fb forward, fully fused: 1 block (256 thr) per walker.
// R4 = R1 skeleton (phase-sequential weight access -> L2-friendly) +
//   float4 LDS broadcast reads, 4-batched W loads in svT loop,
//   fast tanh/exp, single-pass p-stream, float4 residual update.
// f32 numerics everywhere. 2 blocks/CU (LDS ~80KB).

namespace {

constexpr float SQRT3 = 1.7320508075688772f;

__device__ __forceinline__ float tanh_fast(float x) {
  float e = __expf(2.f * x);
  return 1.f - 2.f * __builtin_amdgcn_rcpf(e + 1.f);
}

__global__ __launch_bounds__(256, 2) void ansatz_fused(
    const float* __restrict__ r,     // [B,20,3]
    const float* __restrict__ a_g,   // [4,3]
    const float* __restrict__ s_w0,  // [56,256]
    const float* __restrict__ s_b0,  // [256]
    const float* __restrict__ s_w,   // [3,832,256]
    const float* __restrict__ s_b,   // [3,256]
    const float* __restrict__ p_w0,  // [4,32]
    const float* __restrict__ p_b0,  // [32]
    const float* __restrict__ p_w,   // [3,32,32]
    const float* __restrict__ p_b,   // [3,32]
    const float* __restrict__ vu_w, const float* __restrict__ vu_b,
    const float* __restrict__ vd_w, const float* __restrict__ vd_b,
    const float* __restrict__ wu_w, const float* __restrict__ wu_b,
    const float* __restrict__ wd_w, const float* __restrict__ wd_b,
    const float* __restrict__ wf_w,  // [16]
    float* __restrict__ out)         // [B]
{
  const int b = blockIdx.x;
  const int tid = threadIdx.x;

  __shared__ __align__(16) float svT[256 * 20];   // 20480 B (later: orb)
  __shared__ __align__(16) float pv[12800];       // 51200 B (later: suT/sdT)
  __shared__ __align__(16) float mu[256], md[256];
  __shared__ __align__(16) float puT[640], pdT[640];
  __shared__ float lenT[80];
  __shared__ float rl[20][3];
  __shared__ float apos[4][3];
  __shared__ float expv[20];
  __shared__ float lu_s[32], sg_s[32];

  // ---- geometry ----
  if (tid < 60) (&rl[0][0])[tid] = r[b * 60 + tid];
  if (tid >= 64 && tid < 76) (&apos[0][0])[tid - 64] = a_g[tid - 64];
  __syncthreads();

  if (tid < 80) {
    int at = tid / 20, e = tid % 20;
    float dx = rl[e][0] - apos[at][0];
    float dy = rl[e][1] - apos[at][1];
    float dz = rl[e][2] - apos[at][2];
    lenT[tid] = sqrtf(dx * dx + dy * dy + dz * dz);
  }
  // layer-0 pair means directly from geometry
  if (tid < 160) {
    int half = tid / 80, rem = tid % 80, c = rem / 20, j2 = rem % 20;
    float s = 0.f;
    for (int i = half * 10; i < half * 10 + 10; ++i) {
      if (c < 3) {
        s += rl[j2][c] - rl[i][c];
      } else if (i == j2) {
        s += SQRT3;
      } else {
        float dx = rl[j2][0] - rl[i][0], dy = rl[j2][1] - rl[i][1], dz = rl[j2][2] - rl[i][2];
        s += sqrtf(dx * dx + dy * dy + dz * dz);
      }
    }
    (half ? pdT : puT)[c * 20 + j2] = s * 0.1f;
  }
  __syncthreads();

  if (tid < 20) {
    float s = 0.f;
#pragma unroll
    for (int at = 0; at < 4; ++at) s += __expf(-lenT[at * 20 + tid]);
    expv[tid] = s;
  }
  if (tid < 32) {
    int k = tid & 15, half = tid >> 4;
    int at = k >> 2, comp = k & 3;
    float s = 0.f;
    for (int e = half * 10; e < half * 10 + 10; ++e)
      s += (comp < 3) ? (rl[e][comp] - apos[at][comp]) : lenT[at * 20 + e];
    (half ? md : mu)[k] = s * 0.1f;
  }
  __syncthreads();

  // ---- layer 0, single stream ----
  {
    const int j = tid;
    float w0s[16], wpp[8];
#pragma unroll
    for (int k = 0; k < 16; ++k) w0s[k] = s_w0[k * 256 + j];
#pragma unroll
    for (int c = 0; c < 8; ++c) wpp[c] = s_w0[(48 + c) * 256 + j];
    float accm = s_b0[j];
#pragma unroll
    for (int k = 0; k < 16; ++k)
      accm += mu[k] * s_w0[(16 + k) * 256 + j] + md[k] * s_w0[(32 + k) * 256 + j];
    float sv0[20];
#pragma unroll
    for (int e = 0; e < 20; ++e) {
      float acc = accm;
#pragma unroll
      for (int at = 0; at < 4; ++at) {
        acc += (rl[e][0] - apos[at][0]) * w0s[at * 4 + 0];
        acc += (rl[e][1] - apos[at][1]) * w0s[at * 4 + 1];
        acc += (rl[e][2] - apos[at][2]) * w0s[at * 4 + 2];
        acc += lenT[at * 20 + e] * w0s[at * 4 + 3];
      }
#pragma unroll
      for (int c = 0; c < 4; ++c)
        acc += puT[c * 20 + e] * wpp[c] + pdT[c * 20 + e] * wpp[4 + c];
      sv0[e] = tanh_fast(acc);
    }
#pragma unroll
    for (int e = 0; e < 20; ++e) svT[j * 20 + e] = sv0[e];
  }
  // ---- layer 0, pair stream ----
  {
    const int c = tid & 31;
    float pw0c[4];
#pragma unroll
    for (int k = 0; k < 4; ++k) pw0c[k] = p_w0[k * 32 + c];
    const float pb0c = p_b0[c];
    for (int s = 0; s < 50; ++s) {
      int o = tid + 256 * s;
      int ij = o >> 5, i = ij / 20, j2 = ij % 20;
      float dx = rl[j2][0] - rl[i][0], dy = rl[j2][1] - rl[i][1], dz = rl[j2][2] - rl[i][2];
      float len = (i == j2) ? SQRT3 : sqrtf(dx * dx + dy * dy + dz * dz);
      pv[o] = tanh_fast(pb0c + dx * pw0c[0] + dy * pw0c[1] + dz * pw0c[2] + len * pw0c[3]);
    }
  }
  __syncthreads();

  // ---- residual layers + final means pass ----
  for (int l = 0; l < 4; ++l) {
    // s means (float4 reads of own row; once per layer, conflicts negligible)
    {
      const float4* svr = (const float4*)&svT[tid * 20];
      float4 a0 = svr[0], a1 = svr[1], a2 = svr[2], a3 = svr[3], a4 = svr[4];
      mu[tid] = (a0.x + a0.y + a0.z + a0.w + a1.x + a1.y + a1.z + a1.w + a2.x + a2.y) * 0.1f;
      md[tid] = (a2.z + a2.w + a3.x + a3.y + a3.z + a3.w + a4.x + a4.y + a4.z + a4.w) * 0.1f;
    }
    // pair means
#pragma unroll
    for (int t5 = 0; t5 < 5; ++t5) {
      int t = tid + 256 * t5;
      int half = t / 640, rem = t % 640, j2 = rem >> 5, c = rem & 31;
      int base = half * 6400 + j2 * 32 + c;
      float s = 0.f;
#pragma unroll
      for (int i = 0; i < 10; ++i) s += pv[base + i * 640];
      (half ? pdT : puT)[c * 20 + j2] = s * 0.1f;
    }
    __syncthreads();
    if (l == 3) break;

    const float* Wj = s_w + l * 832 * 256 + tid;
    const float* PW = p_w + l * 1024;

    // ---- single stream: thread j = tid owns output column j ----
    float sacc[20];
#pragma unroll
    for (int e = 0; e < 20; ++e) sacc[e] = 0.f;

    // phase 1: means contribution (sequential region 256..768)
    float m0 = 0.f, m1 = 0.f, m2 = 0.f, m3 = 0.f;
    for (int k0 = 0; k0 < 256; k0 += 8) {
      float wu8[8], wd8[8];
#pragma unroll
      for (int i = 0; i < 8; ++i) {
        wu8[i] = Wj[(256 + k0 + i) * 256];
        wd8[i] = Wj[(512 + k0 + i) * 256];
      }
      float muv[8], mdv[8];
      *(float4*)&muv[0] = *(const float4*)&mu[k0];
      *(float4*)&muv[4] = *(const float4*)&mu[k0 + 4];
      *(float4*)&mdv[0] = *(const float4*)&md[k0];
      *(float4*)&mdv[4] = *(const float4*)&md[k0 + 4];
#pragma unroll
      for (int i = 0; i < 8; i += 2) {
        m0 = fmaf(muv[i], wu8[i], m0);         m1 = fmaf(mdv[i], wd8[i], m1);
        m2 = fmaf(muv[i + 1], wu8[i + 1], m2); m3 = fmaf(mdv[i + 1], wd8[i + 1], m3);
      }
    }

    // phase 2: svT contribution (sequential region 0..256), 4 loads in flight
    for (int k0 = 0; k0 < 256; k0 += 4) {
      float w4[4];
#pragma unroll
      for (int i = 0; i < 4; ++i) w4[i] = Wj[(k0 + i) * 256];
#pragma unroll
      for (int i = 0; i < 4; ++i) {
        const float4* rw = (const float4*)&svT[(k0 + i) * 20];
        float4 r0 = rw[0], r1 = rw[1], r2 = rw[2], r3 = rw[3], r4 = rw[4];
        const float w = w4[i];
        sacc[0] = fmaf(r0.x, w, sacc[0]);   sacc[1] = fmaf(r0.y, w, sacc[1]);
        sacc[2] = fmaf(r0.z, w, sacc[2]);   sacc[3] = fmaf(r0.w, w, sacc[3]);
        sacc[4] = fmaf(r1.x, w, sacc[4]);   sacc[5] = fmaf(r1.y, w, sacc[5]);
        sacc[6] = fmaf(r1.z, w, sacc[6]);   sacc[7] = fmaf(r1.w, w, sacc[7]);
        sacc[8] = fmaf(r2.x, w, sacc[8]);   sacc[9] = fmaf(r2.y, w, sacc[9]);
        sacc[10] = fmaf(r2.z, w, sacc[10]); sacc[11] = fmaf(r2.w, w, sacc[11]);
        sacc[12] = fmaf(r3.x, w, sacc[12]); sacc[13] = fmaf(r3.y, w, sacc[13]);
        sacc[14] = fmaf(r3.z, w, sacc[14]); sacc[15] = fmaf(r3.w, w, sacc[15]);
        sacc[16] = fmaf(r4.x, w, sacc[16]); sacc[17] = fmaf(r4.y, w, sacc[17]);
        sacc[18] = fmaf(r4.z, w, sacc[18]); sacc[19] = fmaf(r4.w, w, sacc[19]);
      }
    }

    // phase 3: pair contribution (sequential region 768..832)
    for (int c0 = 0; c0 < 32; c0 += 4) {
      float wu4[4], wd4[4];
#pragma unroll
      for (int i = 0; i < 4; ++i) {
        wu4[i] = Wj[(768 + c0 + i) * 256];
        wd4[i] = Wj[(800 + c0 + i) * 256];
      }
#pragma unroll
      for (int i = 0; i < 4; ++i) {
        const float4* pu4 = (const float4*)&puT[(c0 + i) * 20];
        const float4* pd4 = (const float4*)&pdT[(c0 + i) * 20];
        float4 u0 = pu4[0], u1 = pu4[1], u2 = pu4[2], u3 = pu4[3], u4 = pu4[4];
        float4 d0 = pd4[0], d1 = pd4[1], d2 = pd4[2], d3 = pd4[3], d4 = pd4[4];
        const float wu = wu4[i], wd = wd4[i];
        sacc[0] = fmaf(d0.x, wd, fmaf(u0.x, wu, sacc[0]));
        sacc[1] = fmaf(d0.y, wd, fmaf(u0.y, wu, sacc[1]));
        sacc[2] = fmaf(d0.z, wd, fmaf(u0.z, wu, sacc[2]));
        sacc[3] = fmaf(d0.w, wd, fmaf(u0.w, wu, sacc[3]));
        sacc[4] = fmaf(d1.x, wd, fmaf(u1.x, wu, sacc[4]));
        sacc[5] = fmaf(d1.y, wd, fmaf(u1.y, wu, sacc[5]));
        sacc[6] = fmaf(d1.z, wd, fmaf(u1.z, wu, sacc[6]));
        sacc[7] = fmaf(d1.w, wd, fmaf(u1.w, wu, sacc[7]));
        sacc[8] = fmaf(d2.x, wd, fmaf(u2.x, wu, sacc[8]));
        sacc[9] = fmaf(d2.y, wd, fmaf(u2.y, wu, sacc[9]));
        sacc[10] = fmaf(d2.z, wd, fmaf(u2.z, wu, sacc[10]));
        sacc[11] = fmaf(d2.w, wd, fmaf(u2.w, wu, sacc[11]));
        sacc[12] = fmaf(d3.x, wd, fmaf(u3.x, wu, sacc[12]));
        sacc[13] = fmaf(d3.y, wd, fmaf(u3.y, wu, sacc[13]));
        sacc[14] = fmaf(d3.z, wd, fmaf(u3.z, wu, sacc[14]));
        sacc[15] = fmaf(d3.w, wd, fmaf(u3.w, wu, sacc[15]));
        sacc[16] = fmaf(d4.x, wd, fmaf(u4.x, wu, sacc[16]));
        sacc[17] = fmaf(d4.y, wd, fmaf(u4.y, wu, sacc[17]));
        sacc[18] = fmaf(d4.z, wd, fmaf(u4.z, wu, sacc[18]));
        sacc[19] = fmaf(d4.w, wd, fmaf(u4.w, wu, sacc[19]));
      }
    }

    float accm = s_b[l * 256 + tid] + ((m0 + m1) + (m2 + m3));
#pragma unroll
    for (int e = 0; e < 20; ++e) sacc[e] = tanh_fast(sacc[e] + accm);
    __syncthreads();
    // residual update, float4
    {
      float4* svr = (float4*)&svT[tid * 20];
#pragma unroll
      for (int q = 0; q < 5; ++q) {
        float4 v = svr[q];
        v.x += sacc[4 * q + 0]; v.y += sacc[4 * q + 1];
        v.z += sacc[4 * q + 2]; v.w += sacc[4 * q + 3];
        svr[q] = v;
      }
    }

    // ---- pair stream: single pass; row owned end-to-end by one wave ----
    {
      const int c = tid & 31;
      float pwc[32];
#pragma unroll
      for (int k = 0; k < 32; ++k) pwc[k] = PW[k * 32 + c];
      const float pbc = p_b[l * 32 + c];
      for (int s = 0; s < 50; ++s) {
        int o = tid + 256 * s;
        const float4* q4 = (const float4*)&pv[(o >> 5) << 5];
        float row[32];
#pragma unroll
        for (int q = 0; q < 8; ++q) *(float4*)&row[4 * q] = q4[q];
        float acc = pbc;
#pragma unroll
        for (int k = 0; k < 32; ++k) acc = fmaf(row[k], pwc[k], acc);
        pv[o] = row[c] + tanh_fast(acc);
      }
    }
    __syncthreads();
  }

  // ---- vu/vd heads: suT/sdT overlay the (dead) pv region ----
  float* suT = pv;             // [256][12]
  float* sdT = pv + 256 * 12;
  {
    const int j = tid;
#pragma unroll
    for (int sS = 0; sS < 2; ++sS) {
      const float* Wj = (sS ? vd_w : vu_w) + j;
      const float* Bv = sS ? vd_b : vu_b;
      float* dst = sS ? sdT : suT;
      float acc[10];
#pragma unroll
      for (int e = 0; e < 10; ++e) acc[e] = 0.f;

      float m0 = 0.f, m1 = 0.f, m2 = 0.f, m3 = 0.f;
      for (int k0 = 0; k0 < 256; k0 += 8) {
        float wu8[8], wd8[8];
#pragma unroll
        for (int i = 0; i < 8; ++i) {
          wu8[i] = Wj[(256 + k0 + i) * 256];
          wd8[i] = Wj[(512 + k0 + i) * 256];
        }
        float muv[8], mdv[8];
        *(float4*)&muv[0] = *(const float4*)&mu[k0];
        *(float4*)&muv[4] = *(const float4*)&mu[k0 + 4];
        *(float4*)&mdv[0] = *(const float4*)&md[k0];
        *(float4*)&mdv[4] = *(const float4*)&md[k0 + 4];
#pragma unroll
        for (int i = 0; i < 8; i += 2) {
          m0 = fmaf(muv[i], wu8[i], m0);         m1 = fmaf(mdv[i], wd8[i], m1);
          m2 = fmaf(muv[i + 1], wu8[i + 1], m2); m3 = fmaf(mdv[i + 1], wd8[i + 1], m3);
        }
      }

      for (int k0 = 0; k0 < 256; k0 += 4) {
        float w4[4];
#pragma unroll
        for (int i = 0; i < 4; ++i) w4[i] = Wj[(k0 + i) * 256];
#pragma unroll
        for (int i = 0; i < 4; ++i) {
          const float w = w4[i];
          const float* rowp = &svT[(k0 + i) * 20];
          if (sS == 0) {
            float4 r0 = *(const float4*)&rowp[0];
            float4 r1 = *(const float4*)&rowp[4];
            float2 r2 = *(const float2*)&rowp[8];
            acc[0] = fmaf(r0.x, w, acc[0]); acc[1] = fmaf(r0.y, w, acc[1]);
            acc[2] = fmaf(r0.z, w, acc[2]); acc[3] = fmaf(r0.w, w, acc[3]);
            acc[4] = fmaf(r1.x, w, acc[4]); acc[5] = fmaf(r1.y, w, acc[5]);
            acc[6] = fmaf(r1.z, w, acc[6]); acc[7] = fmaf(r1.w, w, acc[7]);
            acc[8] = fmaf(r2.x, w, acc[8]); acc[9] = fmaf(r2.y, w, acc[9]);
          } else {
            float2 r0 = *(const float2*)&rowp[10];
            float4 r1 = *(const float4*)&rowp[12];
            float4 r2 = *(const float4*)&rowp[16];
            acc[0] = fmaf(r0.x, w, acc[0]); acc[1] = fmaf(r0.y, w, acc[1]);
            acc[2] = fmaf(r1.x, w, acc[2]); acc[3] = fmaf(r1.y, w, acc[3]);
            acc[4] = fmaf(r1.z, w, acc[4]); acc[5] = fmaf(r1.w, w, acc[5]);
            acc[6] = fmaf(r2.x, w, acc[6]); acc[7] = fmaf(r2.y, w, acc[7]);
            acc[8] = fmaf(r2.z, w, acc[8]); acc[9] = fmaf(r2.w, w, acc[9]);
          }
        }
      }

      const int e0 = sS * 10;
      for (int c0 = 0; c0 < 32; c0 += 4) {
        float wu4[4], wd4[4];
#pragma unroll
        for (int i = 0; i < 4; ++i) {
          wu4[i] = Wj[(768 + c0 + i) * 256];
          wd4[i] = Wj[(800 + c0 + i) * 256];
        }
#pragma unroll
        for (int i = 0; i < 4; ++i) {
#pragma unroll
          for (int e = 0; e < 10; ++e)
            acc[e] = fmaf(pdT[(c0 + i) * 20 + e0 + e], wd4[i],
                     fmaf(puT[(c0 + i) * 20 + e0 + e], wu4[i], acc[e]));
        }
      }
      float accm = Bv[j] + ((m0 + m1) + (m2 + m3));
#pragma unroll
      for (int e = 0; e < 10; ++e) dst[j * 12 + e] = tanh_fast(acc[e] + accm);
    }
  }
  __syncthreads();

  // ---- orbital matrices (orb overlays dead svT) ----
  float* orb = svT;  // [32][100]
  for (int t = tid; t < 320; t += 256) {
    const int mat = t / 160, col = t % 160;
    const float* Wc = (mat ? wd_w : wu_w) + col;
    const float* Bv = mat ? wd_b : wu_b;
    const float* src = mat ? sdT : suT;
    float acc[10];
#pragma unroll
    for (int e = 0; e < 10; ++e) acc[e] = 0.f;
    for (int k0 = 0; k0 < 256; k0 += 8) {
      float w8[8];
#pragma unroll
      for (int i = 0; i < 8; ++i) w8[i] = Wc[(k0 + i) * 160];
#pragma unroll
      for (int i = 0; i < 8; ++i) {
        const float* rowp = &src[(k0 + i) * 12];
        float4 r0 = *(const float4*)&rowp[0];
        float4 r1 = *(const float4*)&rowp[4];
        float2 r2 = *(const float2*)&rowp[8];
        const float w = w8[i];
        acc[0] = fmaf(r0.x, w, acc[0]); acc[1] = fmaf(r0.y, w, acc[1]);
        acc[2] = fmaf(r0.z, w, acc[2]); acc[3] = fmaf(r0.w, w, acc[3]);
        acc[4] = fmaf(r1.x, w, acc[4]); acc[5] = fmaf(r1.y, w, acc[5]);
        acc[6] = fmaf(r1.z, w, acc[6]); acc[7] = fmaf(r1.w, w, acc[7]);
        acc[8] = fmaf(r2.x, w, acc[8]); acc[9] = fmaf(r2.y, w, acc[9]);
      }
    }
    const float bb = Bv[col];
    const int d = col / 10, jo = col % 10;
#pragma unroll
    for (int e = 0; e < 10; ++e)
      orb[(mat * 16 + d) * 100 + e * 10 + jo] = (acc[e] + bb) * expv[mat * 10 + e];
  }
  __syncthreads();

  // ---- slogdet: one 10x10 partial-pivot LU per thread ----
  if (tid < 32) {
    float* M = orb + tid * 100;
    float ldet = 0.f, sg = 1.f;
    for (int c = 0; c < 10; ++c) {
      int p = c;
      float mx = fabsf(M[c * 10 + c]);
      for (int rr = c + 1; rr < 10; ++rr) {
        float v = fabsf(M[rr * 10 + c]);
        if (v > mx) { mx = v; p = rr; }
      }
      if (p != c) {
        sg = -sg;
        for (int cc = c; cc < 10; ++cc) {
          float tmp = M[c * 10 + cc];
          M[c * 10 + cc] = M[p * 10 + cc];
          M[p * 10 + cc] = tmp;
        }
      }
      float piv = M[c * 10 + c];
      if (piv < 0.f) sg = -sg;
      ldet += logf(fabsf(piv));
      float inv = 1.f / piv;
      for (int rr = c + 1; rr < 10; ++rr) {
        float f = M[rr * 10 + c] * inv;
        for (int cc = c + 1; cc < 10; ++cc) M[rr * 10 + cc] -= f * M[c * 10 + cc];
      }
    }
    lu_s[tid] = ldet;
    sg_s[tid] = sg;
  }
  __syncthreads();

  if (tid == 0) {
    float mx = -1e30f;
    float l[16], sgn[16];
#pragma unroll
    for (int d = 0; d < 16; ++d) {
      l[d] = lu_s[d] + lu_s[16 + d];
      sgn[d] = sg_s[d] * sg_s[16 + d];
      mx = fmaxf(mx, l[d]);
    }
    float psi = 0.f;
#pragma unroll
    for (int d = 0; d < 16; ++d) psi += sgn[d] * __expf(l[d] - mx) * wf_w[d];
    out[b] = logf(fabsf(psi)) + mx;
  }
}

}  // namespace

extern "C" void kernel_launch(void* const* d_in, const int* in_sizes, int n_in,
                              void* d_out, int out_size, void* d_ws, size_t ws_size,
                              hipStream_t stream) {
  const float* r = (const float*)d_in[0];
  const float* a = (const float*)d_in[1];
  const float* s_w0 = (const float*)d_in[2];
  const float* s_b0 = (const float*)d_in[3];
  const float* s_w = (const float*)d_in[4];
  const float* s_b = (const float*)d_in[5];
  const float* p_w0 = (const float*)d_in[6];
  const float* p_b0 = (const float*)d_in[7];
  const float* p_w = (const float*)d_in[8];
  const float* p_b = (const float*)d_in[9];
  const float* vu_w = (const float*)d_in[10];
  const float* vu_b = (const float*)d_in[11];
  const float* vd_w = (const float*)d_in[12];
  const float* vd_b = (const float*)d_in[13];
  const float* wu_w = (const float*)d_in[14];
  const float* wu_b = (const float*)d_in[15];
  const float* wd_w = (const float*)d_in[16];
  const float* wd_b = (const float*)d_in[17];
  const float* wf_w = (const float*)d_in[18];

  const int nb = in_sizes[0] / 60;  // [B,20,3]
  ansatz_fused<<<dim3(nb), dim3(256), 0, stream>>>(
      r, a, s_w0, s_b0, s_w, s_b, p_w0, p_b0, p_w, p_b,
      vu_w, vu_b, vd_w, vd_b, wu_w, wu_b, wd_w, wd_b, wf_w,
      (float*)d_out);
}